// Round 10
// baseline (150.599 us; speedup 1.0000x reference)
//
#include <hip/hip_runtime.h>
#include <hip/hip_bf16.h>
#include <stdint.h>

#define T_SEQ 4096

typedef float  f32x4   __attribute__((ext_vector_type(4)));
typedef float  f32x16  __attribute__((ext_vector_type(16)));
typedef short  bf16x8  __attribute__((ext_vector_type(8)));
typedef unsigned int u32x4 __attribute__((ext_vector_type(4)));

typedef const __attribute__((address_space(1))) uint32_t* gptr_t;
typedef __attribute__((address_space(3))) uint32_t* lptr_t;

__device__ __forceinline__ uint32_t f2bf1(float f) {
    uint32_t u = __float_as_uint(f);
    return (u + 0x7fffu + ((u >> 16) & 1u)) >> 16;   // RNE f32->bf16
}
__device__ __forceinline__ short f2bfs(float f) { return (short)f2bf1(f); }
__device__ __forceinline__ uint32_t cvtpk(float lo, float hi) {
    uint32_t r;
    asm("v_cvt_pk_bf16_f32 %0, %1, %2" : "=v"(r) : "v"(lo), "v"(hi));
    return r;
}

// ---------------------------------------------------------------------------
// Kernel 1: Q,K projections. Q pre-scaled by 0.125*log2(e) (softmax uses 2^x).
// Layout: [bh=b*2+h][t][64] bf16.
// ---------------------------------------------------------------------------
__global__ __launch_bounds__(256) void qk_proj(
    const float* __restrict__ x,
    const float* __restrict__ Wq1, const float* __restrict__ Wk1,
    const float* __restrict__ Wq2, const float* __restrict__ Wk2,
    short* __restrict__ Q, short* __restrict__ K)
{
    int idx = blockIdx.x * 256 + threadIdx.x;
    int d = idx & 63;
    int t = (idx >> 6) & (T_SEQ - 1);
    int b = idx >> 18;
    const float* xp = x + (size_t)(b * T_SEQ + t) * 6;
    float x0 = xp[0], x1 = xp[1], x2 = xp[2];
    float x3 = xp[3], x4 = xp[4], x5 = xp[5];
    const float QS = 0.125f * 1.44269504088896340736f;
    float q1 = (x0 * Wq1[d] + x1 * Wq1[64 + d] + x2 * Wq1[128 + d]) * QS;
    float k1 =  x0 * Wk1[d] + x1 * Wk1[64 + d] + x2 * Wk1[128 + d];
    float q2 = (x3 * Wq2[d] + x4 * Wq2[64 + d] + x5 * Wq2[128 + d]) * QS;
    float k2 =  x3 * Wk2[d] + x4 * Wk2[64 + d] + x5 * Wk2[128 + d];
    size_t base1 = ((size_t)(b * 2 + 0) * T_SEQ + t) * 64 + d;
    size_t base2 = ((size_t)(b * 2 + 1) * T_SEQ + t) * 64 + d;
    Q[base1] = f2bfs(q1);  Q[base2] = f2bfs(q2);
    K[base1] = f2bfs(k1);  K[base2] = f2bfs(k2);
}

// ---------------------------------------------------------------------------
// Kernel 2: V projection written FRAGMENT-MAJOR for register PV fragments:
//   Vf[bh][c=t>>6][half=(t>>5)&1][m(4)][lane(64)][e(8)] bf16, where the attn
//   wave (any tile, kv-half `half`) reads fragment m as a CONTIGUOUS 1KB
//   load: lane l gets 16B at seg + m*1024B + l*16B ==
//     m=0: V[d=l&31   ][kv = 64c+32*half+ 8*(l>>5)+e]
//     m=1: V[d=l&31   ][kv = ... +16]
//     m=2: V[d=32+l&31][kv = ... ]        m=3: m=2 row, kv+16
//   (exactly R8's ldsV read set). Element (t,d) mapping:
//     kvq=t&31; m=2*(d>>5)+(kvq>>4); l=(d&31)+32*((kvq>>3)&1); e=kvq&7.
// ---------------------------------------------------------------------------
__global__ __launch_bounds__(256) void v_proj_t(
    const float* __restrict__ x,
    const float* __restrict__ Wv1, const float* __restrict__ Wv2,
    short* __restrict__ Vf)
{
    int bh = blockIdx.x >> 6;
    int tt = blockIdx.x & 63;
    int head = bh & 1, b = bh >> 1;
    int t  = tt * 64 + (threadIdx.x & 63);
    int dg = threadIdx.x >> 6;
    const float* Wv = head ? Wv2 : Wv1;
    const float* xp = x + (size_t)(b * T_SEQ + t) * 6 + head * 3;
    float x0 = xp[0], x1 = xp[1], x2 = xp[2];
    int c = t >> 6, half = (t >> 5) & 1, kvq = t & 31;
    int kvhi = kvq >> 4, hp = (kvq >> 3) & 1, e = kvq & 7;
    size_t segbase = ((size_t)(bh * 64 + c) * 2 + half) * 2048;
    #pragma unroll
    for (int k = 0; k < 16; ++k) {
        int d = dg * 16 + k;
        float v = x0 * Wv[d] + x1 * Wv[64 + d] + x2 * Wv[128 + d];
        int m = 2 * (d >> 5) + kvhi;
        int l = (d & 31) + 32 * hp;
        Vf[segbase + m * 512 + l * 8 + e] = f2bfs(v);
    }
}

// ---------------------------------------------------------------------------
// Kernel 3: causal flash attention = R8 structure + V-in-registers.
//   R9 lesson: fold (fewer waves) loses even with half the pipe work; R8's
//   4-wave (tile,half) blocks + kv-parity split stays. This round removes the
//   V LDS path only: V PV-fragments come from fragment-major Vf as 4 coalesced
//   1KB register loads, depth-1 prefetched (unroll-2 rotation), riding the
//   existing stage->barrier latency window. Removes per body: 2 global_lds,
//   4 ds_read_b128, and the V bank conflicts (the 4-way majority of 4.24M).
//   Regs 84+32=116 <= 128 (16-wave/CU ceiling preserved -- m69 cliff).
//   LDS 32KB -> 17KB (K dbuf 16KB; combine scratch 16.9KB overlaps).
//   Everything else (mask rule, softmax, combine, parity buffers) = R8.
// ---------------------------------------------------------------------------
__global__ __launch_bounds__(256, 4) void attn(
    const short* __restrict__ Q, const short* __restrict__ K,
    const short* __restrict__ Vt, float* __restrict__ Hf,
    float* __restrict__ P1, float* __restrict__ L0, float* __restrict__ L1)
{
    __shared__ __align__(16) char smem[17408];  // K dbuf 2x8K; combine reuses

    int id = blockIdx.x;                 // 2048
    int xcd = id & 7, rest = id >> 3;    // rest 0..255
    int bh = xcd * 2 + (rest & 1);       // 2 bh per XCD (L2 locality)
    int rem = rest >> 1;                 // 0..127
    int s  = 63 - (rem >> 1);            // pair index, LONGEST FIRST
    int p  = rem & 1;                    // kv-parity half
    int tid = threadIdx.x;
    int W = tid >> 6;
    int lane = tid & 63;
    int ql = lane & 31, h = lane >> 5;
    int tile = W >> 1, half = W & 1;     // wave's (tile, kv-half)
    int t0 = 64 * s + 32 * tile;
    int q  = t0 + ql;
    int n  = s + 1;                      // total 64-kv chunks for this pair
    int nb = (n - p + 1) >> 1;           // my chunk count: ceil((n-p)/2)

    size_t kvbase = (size_t)bh * (T_SEQ * 64);

    // Q fragment (B-operand): lane holds Q[q][ks*16 + h*8 + j]
    bf16x8 qf[4];
    #pragma unroll
    for (int ks = 0; ks < 4; ++ks)
        qf[ks] = *(const bf16x8*)(Q + kvbase + (size_t)q * 64 + ks * 16 + h * 8);

    // K staging map (256 threads): row = tid>>3 (0..31), slot = tid&7,
    // pre-swizzled source column; LDS dest linear (swizzle applied on read).
    int krl = tid >> 3;
    int kcol = ((tid & 7) ^ (krl & 7)) * 8;
    const short* ksrc0 = K + kvbase + kcol;              // + srow*64

    f32x16 acc0, acc1;
    #pragma unroll
    for (int rr = 0; rr < 16; ++rr) { acc0[rr] = 0.f; acc1[rr] = 0.f; }
    float l = 0.f;
    int swz = (ql & 7) << 4;

#define STAGE(bsel, kvv)                                                        \
    {                                                                           \
        char* kb = smem + (bsel) * 8192;                                        \
        _Pragma("unroll")                                                       \
        for (int z = 0; z < 2; ++z)                                             \
            __builtin_amdgcn_global_load_lds(                                   \
                (gptr_t)(ksrc0 + (size_t)((kvv) + 32 * z + krl) * 64),          \
                (lptr_t)(kb + z * 4096 + tid * 16), 16, 0, 0);                  \
    }

#define VLOAD(v0, v1, v2, v3, cc)                                               \
    {                                                                           \
        const short* vs = Vt + ((size_t)(bh * 64 + (cc)) * 2 + half) * 2048     \
                             + lane * 8;                                        \
        v0 = *(const bf16x8*)(vs);                                              \
        v1 = *(const bf16x8*)(vs + 512);                                        \
        v2 = *(const bf16x8*)(vs + 1024);                                       \
        v3 = *(const bf16x8*)(vs + 1536);                                       \
    }

#define QK_SM(pf0, pf1)                                                         \
        {                                                                       \
            f32x16 Sv;                                                          \
            _Pragma("unroll") for (int rr = 0; rr < 16; ++rr) Sv[rr] = 0.f;     \
            Sv = __builtin_amdgcn_mfma_f32_32x32x16_bf16(kf0, qf[0], Sv,0,0,0); \
            Sv = __builtin_amdgcn_mfma_f32_32x32x16_bf16(kf1, qf[1], Sv,0,0,0); \
            Sv = __builtin_amdgcn_mfma_f32_32x32x16_bf16(kf2, qf[2], Sv,0,0,0); \
            Sv = __builtin_amdgcn_mfma_f32_32x32x16_bf16(kf3, qf[3], Sv,0,0,0); \
            bool needmask = (kv0 + 32 * half + 31 > t0);  /* max_kv > t0 */     \
            uint32_t pw[8];                                                     \
            float l0 = 0.f, l1 = 0.f;                                           \
            _Pragma("unroll") for (int e = 0; e < 8; ++e) {                     \
                float p0 = __builtin_amdgcn_exp2f(Sv[2 * e]);                   \
                float p1 = __builtin_amdgcn_exp2f(Sv[2 * e + 1]);               \
                if (needmask) {                                                 \
                    int kv = kv0 + 32 * half + 4 * h + 2 * (e & 1) + 8 * (e >> 1); \
                    p0 = (kv     <= q) ? p0 : 0.f;                              \
                    p1 = (kv + 1 <= q) ? p1 : 0.f;                              \
                }                                                               \
                l0 += p0; l1 += p1;                                             \
                pw[e] = cvtpk(p0, p1);                                          \
            }                                                                   \
            l += l0 + l1;                                                       \
            {                                                                   \
                uint32_t a0 = pw[0], b0 = pw[2], a1 = pw[1], b1 = pw[3];        \
                asm("v_permlane32_swap_b32 %0, %1" : "+v"(a0), "+v"(b0));       \
                asm("v_permlane32_swap_b32 %0, %1" : "+v"(a1), "+v"(b1));       \
                u32x4 fr = {a0, a1, b0, b1};                                    \
                pf0 = __builtin_bit_cast(bf16x8, fr);                           \
                uint32_t c0 = pw[4], d0 = pw[6], c1 = pw[5], d1 = pw[7];        \
                asm("v_permlane32_swap_b32 %0, %1" : "+v"(c0), "+v"(d0));       \
                asm("v_permlane32_swap_b32 %0, %1" : "+v"(c1), "+v"(d1));       \
                u32x4 fr1 = {c0, c1, d0, d1};                                   \
                pf1 = __builtin_bit_cast(bf16x8, fr1);                          \
            }                                                                   \
        }

#define BODY(jj, va0, va1, va2, va3, vb0, vb1, vb2, vb3)                        \
    {                                                                           \
        const int kv0 = 64 * (p + 2 * (jj));                                    \
        if ((jj) + 1 < nb) {                                                    \
            STAGE(((jj) + 1) & 1, kv0 + 128);                                   \
            VLOAD(vb0, vb1, vb2, vb3, p + 2 * ((jj) + 1));                      \
        }                                                                       \
        const char* kb = smem + ((jj) & 1) * 8192;                              \
        const char* krw = kb + (32 * half + ql) * 128;                          \
        bf16x8 kf0 = *(const bf16x8*)(krw + ((0 * 32 + h * 16) ^ swz));         \
        bf16x8 kf1 = *(const bf16x8*)(krw + ((1 * 32 + h * 16) ^ swz));         \
        bf16x8 kf2 = *(const bf16x8*)(krw + ((2 * 32 + h * 16) ^ swz));         \
        bf16x8 kf3 = *(const bf16x8*)(krw + ((3 * 32 + h * 16) ^ swz));         \
        bool act = (kv0 + 32 * half <= t0 + 31);                                \
        bf16x8 pf0, pf1;                                                        \
        __builtin_amdgcn_s_setprio(1);                                          \
        if (act) QK_SM(pf0, pf1)                                                \
        if (act) {                                                              \
            acc0 = __builtin_amdgcn_mfma_f32_32x32x16_bf16(va0, pf0, acc0, 0, 0, 0); \
            acc0 = __builtin_amdgcn_mfma_f32_32x32x16_bf16(va1, pf1, acc0, 0, 0, 0); \
            acc1 = __builtin_amdgcn_mfma_f32_32x32x16_bf16(va2, pf0, acc1, 0, 0, 0); \
            acc1 = __builtin_amdgcn_mfma_f32_32x32x16_bf16(va3, pf1, acc1, 0, 0, 0); \
        }                                                                       \
        __builtin_amdgcn_s_setprio(0);                                          \
        __syncthreads();                                                        \
    }

    bf16x8 vA0, vA1, vA2, vA3, vB0, vB1, vB2, vB3;
    if (nb > 0) { STAGE(0, 64 * p); VLOAD(vA0, vA1, vA2, vA3, p); }
    __syncthreads();

    int j = 0;
    if (nb > 0) for (;;) {
        BODY(j, vA0, vA1, vA2, vA3, vB0, vB1, vB2, vB3);
        if (++j >= nb) break;
        BODY(j, vB0, vB1, vB2, vB3, vA0, vA1, vA2, vA3);
        if (++j >= nb) break;
    }
#undef BODY
#undef QK_SM
#undef VLOAD
#undef STAGE

    // ---- combine: 2 partials/tile. half1 publishes, half0 absorbs+writes
    //      UNNORMALIZED partial (acc, l) to this parity's buffers.
    l += __shfl_xor(l, 32);
    float* sg = (float*)smem + tile * 2112 + lane * 33;  // 2 x [64][33] f32
    if (half == 1) {
        #pragma unroll
        for (int g = 0; g < 4; ++g) {
            *(f32x4*)(sg + 4 * g)      = f32x4{acc0[4*g+0], acc0[4*g+1], acc0[4*g+2], acc0[4*g+3]};
            *(f32x4*)(sg + 16 + 4 * g) = f32x4{acc1[4*g+0], acc1[4*g+1], acc1[4*g+2], acc1[4*g+3]};
        }
        sg[32] = l;
    }
    __syncthreads();
    if (half == 0) {
        #pragma unroll
        for (int g = 0; g < 4; ++g) {
            f32x4 u0 = *(f32x4*)(sg + 4 * g);
            f32x4 u1 = *(f32x4*)(sg + 16 + 4 * g);
            acc0[4*g+0] += u0[0]; acc0[4*g+1] += u0[1]; acc0[4*g+2] += u0[2]; acc0[4*g+3] += u0[3];
            acc1[4*g+0] += u1[0]; acc1[4*g+1] += u1[1]; acc1[4*g+2] += u1[2]; acc1[4*g+3] += u1[3];
        }
        l += sg[32];
        int head = bh & 1, bb = bh >> 1;
        float* Pdst = p ? P1 : Hf;
        float* Ldst = p ? L1 : L0;
        float* hp = Pdst + ((size_t)(bb * T_SEQ) + t0 + ql) * 128 + head * 64 + 4 * h;
        #pragma unroll
        for (int g2 = 0; g2 < 4; ++g2) {
            f32x4 s0 = { acc0[g2*4+0], acc0[g2*4+1], acc0[g2*4+2], acc0[g2*4+3] };
            *(f32x4*)(hp + 8 * g2) = s0;               // d = 8*g2+4h+0..3
            f32x4 s1 = { acc1[g2*4+0], acc1[g2*4+1], acc1[g2*4+2], acc1[g2*4+3] };
            *(f32x4*)(hp + 32 + 8 * g2) = s1;          // d = 32+8*g2+4h+0..3
        }
        if (h == 0)                       // one lane per q-row
            Ldst[(size_t)bh * T_SEQ + t0 + ql] = l;
    }
}

// ---------------------------------------------------------------------------
// Kernel 4a: one-shot Wout -> Wt bf16, transposed + xor-swizzled for LDS.
// ---------------------------------------------------------------------------
__global__ __launch_bounds__(256) void prep_wt(
    const float* __restrict__ Wout, short* __restrict__ Wt)
{
    int tid = blockIdx.x * 256 + threadIdx.x;   // 16384
    int j = tid >> 7, k = tid & 127;
    float v = Wout[k * 128 + j];
    int slot = k >> 3;
    Wt[j * 128 + (((slot ^ (j & 7)) << 3) | (k & 7))] = f2bfs(v);
}

// ---------------------------------------------------------------------------
// Kernel 4b: out = ((P0+P1) * 1/(L0+L1)) @ Wout -> f32 (in place over P0).
// Row-block-diagonal: each wave reads only its own 16 rows before writing.
// Normalization folded into the bf16 fragment build (per-head rl).
// ---------------------------------------------------------------------------
__global__ __launch_bounds__(256) void out_proj(
    const float* P0, const float* __restrict__ P1,
    const float* __restrict__ L0, const float* __restrict__ L1,
    const short* __restrict__ Wt, float* out)
{
    __shared__ __align__(16) char lws[32768];
    int tid = threadIdx.x;
    int w = tid >> 6, lane = tid & 63, c = lane & 15, g = lane >> 4;
    int cs = c & 7;
    #pragma unroll
    for (int z = 0; z < 8; ++z)
        __builtin_amdgcn_global_load_lds((gptr_t)(Wt + z * 2048 + w * 512 + lane * 8),
                                         (lptr_t)(lws + z * 4096 + w * 1024), 16, 0, 0);
    __syncthreads();

    int row0 = blockIdx.x * 64 + w * 16;
    int r = row0 + c;
    int b = r >> 12, t = r & (T_SEQ - 1);
    float rl0 = 1.0f / (L0[(size_t)(b * 2 + 0) * T_SEQ + t] + L1[(size_t)(b * 2 + 0) * T_SEQ + t]);
    float rl1 = 1.0f / (L0[(size_t)(b * 2 + 1) * T_SEQ + t] + L1[(size_t)(b * 2 + 1) * T_SEQ + t]);

    bf16x8 af[4];
    const float* hp0 = P0 + (size_t)r * 128 + g * 8;
    const float* hp1 = P1 + (size_t)r * 128 + g * 8;
    #pragma unroll
    for (int kc = 0; kc < 4; ++kc) {
        float rl = (kc < 2) ? rl0 : rl1;          // d = kc*32+g*8+.. ; head = d>>6
        f32x4 x0 = *(const f32x4*)(hp0 + kc * 32);
        f32x4 x1 = *(const f32x4*)(hp0 + kc * 32 + 4);
        f32x4 y0 = *(const f32x4*)(hp1 + kc * 32);
        f32x4 y1 = *(const f32x4*)(hp1 + kc * 32 + 4);
        u32x4 wv = { cvtpk((x0[0]+y0[0])*rl, (x0[1]+y0[1])*rl),
                     cvtpk((x0[2]+y0[2])*rl, (x0[3]+y0[3])*rl),
                     cvtpk((x1[0]+y1[0])*rl, (x1[1]+y1[1])*rl),
                     cvtpk((x1[2]+y1[2])*rl, (x1[3]+y1[3])*rl) };
        af[kc] = __builtin_bit_cast(bf16x8, wv);
    }
    #pragma unroll
    for (int jt = 0; jt < 8; ++jt) {
        f32x4 accum = {0.f, 0.f, 0.f, 0.f};
        #pragma unroll
        for (int kc = 0; kc < 4; ++kc) {
            int row = jt * 16 + c;
            bf16x8 bfr = *(const bf16x8*)(lws + row * 256 + (((kc * 4 + g) ^ cs) << 4));
            accum = __builtin_amdgcn_mfma_f32_16x16x32_bf16(af[kc], bfr, accum, 0, 0, 0);
        }
        #pragma unroll
        for (int rr = 0; rr < 4; ++rr)
            out[(size_t)(row0 + g * 4 + rr) * 128 + jt * 16 + c] = accum[rr];
    }
}

// ---------------------------------------------------------------------------
extern "C" void kernel_launch(void* const* d_in, const int* in_sizes, int n_in,
                              void* d_out, int out_size, void* d_ws, size_t ws_size,
                              hipStream_t stream)
{
    (void)in_sizes; (void)n_in; (void)out_size; (void)ws_size;
    const float* x    = (const float*)d_in[0];
    const float* Wq1  = (const float*)d_in[1];
    const float* Wk1  = (const float*)d_in[2];
    const float* Wv1  = (const float*)d_in[3];
    const float* Wq2  = (const float*)d_in[4];
    const float* Wk2  = (const float*)d_in[5];
    const float* Wv2  = (const float*)d_in[6];
    const float* Wout = (const float*)d_in[7];
    float* out = (float*)d_out;

    char* ws = (char*)d_ws;
    short* Q  = (short*)(ws);                               // 8 MiB (dead after attn)
    short* K  = (short*)(ws + (size_t)8  * 1024 * 1024);    // 8 MiB
    short* Vf = (short*)(ws + (size_t)16 * 1024 * 1024);    // 8 MiB fragment-major
    float* P1 = (float*)(ws + (size_t)24 * 1024 * 1024);    // 16 MiB partial
    float* L0 = (float*)(ws + (size_t)40 * 1024 * 1024);    // 256 KiB
    float* L1 = (float*)(ws + (size_t)40 * 1024 * 1024 + 262144);
    short* Wt = Q;                                          // reuse Q region
    float* Hf = out;                                        // P0 lives in d_out

    qk_proj <<<8192, 256, 0, stream>>>(x, Wq1, Wk1, Wq2, Wk2, Q, K);
    v_proj_t<<<1024, 256, 0, stream>>>(x, Wv1, Wv2, Vf);
    attn    <<<2048, 256, 0, stream>>>(Q, K, Vf, Hf, P1, L0, L1);
    prep_wt <<<  64, 256, 0, stream>>>(Wout, Wt);
    out_proj<<< 512, 256, 0, stream>>>(Hf, P1, L0, L1, Wt, out);
}

// Round 11
// 90.490 us; speedup vs baseline: 1.6643x; 1.6643x over previous
//
#include <hip/hip_runtime.h>
#include <hip/hip_bf16.h>
#include <stdint.h>

#define T_SEQ 4096

typedef float  f32x4   __attribute__((ext_vector_type(4)));
typedef float  f32x16  __attribute__((ext_vector_type(16)));
typedef short  bf16x8  __attribute__((ext_vector_type(8)));
typedef unsigned int u32x4 __attribute__((ext_vector_type(4)));

typedef const __attribute__((address_space(1))) uint32_t* gptr_t;
typedef __attribute__((address_space(3))) uint32_t* lptr_t;

__device__ __forceinline__ uint32_t f2bf1(float f) {
    uint32_t u = __float_as_uint(f);
    return (u + 0x7fffu + ((u >> 16) & 1u)) >> 16;   // RNE f32->bf16
}
__device__ __forceinline__ short f2bfs(float f) { return (short)f2bf1(f); }
__device__ __forceinline__ uint32_t cvtpk(float lo, float hi) {
    uint32_t r;
    asm("v_cvt_pk_bf16_f32 %0, %1, %2" : "=v"(r) : "v"(lo), "v"(hi));
    return r;
}

// ---------------------------------------------------------------------------
// Kernel 1: Q,K projections. Q pre-scaled by 0.125*log2(e) (softmax uses 2^x).
// Layout: [bh=b*2+h][t][64] bf16.
// ---------------------------------------------------------------------------
__global__ __launch_bounds__(256) void qk_proj(
    const float* __restrict__ x,
    const float* __restrict__ Wq1, const float* __restrict__ Wk1,
    const float* __restrict__ Wq2, const float* __restrict__ Wk2,
    short* __restrict__ Q, short* __restrict__ K)
{
    int idx = blockIdx.x * 256 + threadIdx.x;
    int d = idx & 63;
    int t = (idx >> 6) & (T_SEQ - 1);
    int b = idx >> 18;
    const float* xp = x + (size_t)(b * T_SEQ + t) * 6;
    float x0 = xp[0], x1 = xp[1], x2 = xp[2];
    float x3 = xp[3], x4 = xp[4], x5 = xp[5];
    const float QS = 0.125f * 1.44269504088896340736f;
    float q1 = (x0 * Wq1[d] + x1 * Wq1[64 + d] + x2 * Wq1[128 + d]) * QS;
    float k1 =  x0 * Wk1[d] + x1 * Wk1[64 + d] + x2 * Wk1[128 + d];
    float q2 = (x3 * Wq2[d] + x4 * Wq2[64 + d] + x5 * Wq2[128 + d]) * QS;
    float k2 =  x3 * Wk2[d] + x4 * Wk2[64 + d] + x5 * Wk2[128 + d];
    size_t base1 = ((size_t)(b * 2 + 0) * T_SEQ + t) * 64 + d;
    size_t base2 = ((size_t)(b * 2 + 1) * T_SEQ + t) * 64 + d;
    Q[base1] = f2bfs(q1);  Q[base2] = f2bfs(q2);
    K[base1] = f2bfs(k1);  K[base2] = f2bfs(k2);
}

// ---------------------------------------------------------------------------
// Kernel 2: V projection written TRANSPOSED: Vt[bh][d][t] bf16. (R8 layout)
// ---------------------------------------------------------------------------
__global__ __launch_bounds__(256) void v_proj_t(
    const float* __restrict__ x,
    const float* __restrict__ Wv1, const float* __restrict__ Wv2,
    short* __restrict__ Vt)
{
    int bh = blockIdx.x >> 6;
    int tt = blockIdx.x & 63;
    int head = bh & 1, b = bh >> 1;
    int t  = tt * 64 + (threadIdx.x & 63);
    int dg = threadIdx.x >> 6;
    const float* Wv = head ? Wv2 : Wv1;
    const float* xp = x + (size_t)(b * T_SEQ + t) * 6 + head * 3;
    float x0 = xp[0], x1 = xp[1], x2 = xp[2];
    size_t base = (size_t)bh * 64 * T_SEQ + t;
    #pragma unroll
    for (int k = 0; k < 16; ++k) {
        int d = dg * 16 + k;
        float v = x0 * Wv[d] + x1 * Wv[64 + d] + x2 * Wv[128 + d];
        Vt[base + (size_t)d * T_SEQ] = f2bfs(v);
    }
}

// ---------------------------------------------------------------------------
// Kernel 3: causal flash attention = R8 structure + COUNTED-VMCNT BARRIERS.
//   R8 accounting: per-body wall 1180 cy vs ~430 cy issue work; the gap is
//   __syncthreads' implicit `s_waitcnt vmcnt(0)` draining the JUST-ISSUED
//   next-chunk stage every body (all-or-nothing drain defeats prefetch; R7
//   proved waves can't hide it). T4 fix, single variable vs R8:
//   - depth-2 staging (chunks j, j+1 in flight; 4 loads/wave each).
//   - body j: vmcnt(4) [retire stage j ONLY] -> s_barrier -> ds_read kf+vf
//     from buf j -> lgkmcnt(0) -> s_barrier [all waves done reading buf j]
//     -> issue stage j+2 into buf j -> MFMA/SM compute.
//     Stage latency gets TWO bodies of cover; vmcnt never 0 in loop.
//   - ghost re-stages keep vmcnt counts uniform at the tail (reload current
//     chunk; same content, race-free; never read).
//   - sched_barrier(0) after each asm wait/barrier (rule #18).
//   - __syncthreads once after loop drains ghosts before combine reuses LDS.
//   Everything else (kv-parity split, V-in-LDS, mask, softmax, combine,
//   parity partial buffers) byte-identical to R8.
// ---------------------------------------------------------------------------
__global__ __launch_bounds__(256, 4) void attn(
    const short* __restrict__ Q, const short* __restrict__ K,
    const short* __restrict__ Vt, float* __restrict__ Hf,
    float* __restrict__ P1, float* __restrict__ L0, float* __restrict__ L1)
{
    __shared__ __align__(16) char smem[32768];  // dbuf 2 x (K 8K + V 8K)

    int id = blockIdx.x;                 // 2048
    int xcd = id & 7, rest = id >> 3;    // rest 0..255
    int bh = xcd * 2 + (rest & 1);       // 2 bh per XCD (L2 locality)
    int rem = rest >> 1;                 // 0..127
    int s  = 63 - (rem >> 1);            // pair index, LONGEST FIRST
    int p  = rem & 1;                    // kv-parity half
    int tid = threadIdx.x;
    int W = tid >> 6;
    int lane = tid & 63;
    int ql = lane & 31, h = lane >> 5;
    int tile = W >> 1, half = W & 1;     // wave's (tile, kv-half)
    int t0 = 64 * s + 32 * tile;
    int q  = t0 + ql;
    int n  = s + 1;                      // total 64-kv chunks for this pair
    int nb = (n - p + 1) >> 1;           // my chunk count: ceil((n-p)/2)

    size_t kvbase = (size_t)bh * (T_SEQ * 64);

    // Q fragment (B-operand): lane holds Q[q][ks*16 + h*8 + j]
    bf16x8 qf[4];
    #pragma unroll
    for (int ks = 0; ks < 4; ++ks)
        qf[ks] = *(const bf16x8*)(Q + kvbase + (size_t)q * 64 + ks * 16 + h * 8);

    // staging maps (256 threads): row = tid>>3 (0..31), slot = tid&7,
    // pre-swizzled source column; LDS dest linear (swizzle applied on read).
    int krl = tid >> 3;
    int kcol = ((tid & 7) ^ (krl & 7)) * 8;
    const short* ksrc0 = K + kvbase + kcol;              // + srow*64
    const short* vsrc0 = Vt + kvbase + kcol;             // + d*T_SEQ + kv

    f32x16 acc0, acc1;
    #pragma unroll
    for (int rr = 0; rr < 16; ++rr) { acc0[rr] = 0.f; acc1[rr] = 0.f; }
    float l = 0.f;
    int swz = (ql & 7) << 4;

#define STAGE(bsel, kvv)                                                        \
    {                                                                           \
        char* kb_ = smem + (bsel) * 16384;                                      \
        char* vb_ = kb_ + 8192;                                                 \
        _Pragma("unroll")                                                       \
        for (int z = 0; z < 2; ++z)                                             \
            __builtin_amdgcn_global_load_lds(                                   \
                (gptr_t)(ksrc0 + (size_t)((kvv) + 32 * z + krl) * 64),          \
                (lptr_t)(kb_ + z * 4096 + tid * 16), 16, 0, 0);                 \
        _Pragma("unroll")                                                       \
        for (int z = 0; z < 2; ++z)                                             \
            __builtin_amdgcn_global_load_lds(                                   \
                (gptr_t)(vsrc0 + (size_t)(32 * z + krl) * T_SEQ + (kvv)),       \
                (lptr_t)(vb_ + z * 4096 + tid * 16), 16, 0, 0);                 \
    }

#define QK_SM(pf0, pf1)                                                         \
        {                                                                       \
            f32x16 Sv;                                                          \
            _Pragma("unroll") for (int rr = 0; rr < 16; ++rr) Sv[rr] = 0.f;     \
            Sv = __builtin_amdgcn_mfma_f32_32x32x16_bf16(kf0, qf[0], Sv,0,0,0); \
            Sv = __builtin_amdgcn_mfma_f32_32x32x16_bf16(kf1, qf[1], Sv,0,0,0); \
            Sv = __builtin_amdgcn_mfma_f32_32x32x16_bf16(kf2, qf[2], Sv,0,0,0); \
            Sv = __builtin_amdgcn_mfma_f32_32x32x16_bf16(kf3, qf[3], Sv,0,0,0); \
            bool needmask = (kv0 + 32 * half + 31 > t0);  /* max_kv > t0 */     \
            uint32_t pw[8];                                                     \
            float l0 = 0.f, l1 = 0.f;                                           \
            _Pragma("unroll") for (int e = 0; e < 8; ++e) {                     \
                float p0 = __builtin_amdgcn_exp2f(Sv[2 * e]);                   \
                float p1 = __builtin_amdgcn_exp2f(Sv[2 * e + 1]);               \
                if (needmask) {                                                 \
                    int kv = kv0 + 32 * half + 4 * h + 2 * (e & 1) + 8 * (e >> 1); \
                    p0 = (kv     <= q) ? p0 : 0.f;                              \
                    p1 = (kv + 1 <= q) ? p1 : 0.f;                              \
                }                                                               \
                l0 += p0; l1 += p1;                                             \
                pw[e] = cvtpk(p0, p1);                                          \
            }                                                                   \
            l += l0 + l1;                                                       \
            {                                                                   \
                uint32_t a0 = pw[0], b0 = pw[2], a1 = pw[1], b1 = pw[3];        \
                asm("v_permlane32_swap_b32 %0, %1" : "+v"(a0), "+v"(b0));       \
                asm("v_permlane32_swap_b32 %0, %1" : "+v"(a1), "+v"(b1));       \
                u32x4 fr = {a0, a1, b0, b1};                                    \
                pf0 = __builtin_bit_cast(bf16x8, fr);                           \
                uint32_t c0 = pw[4], d0 = pw[6], c1 = pw[5], d1 = pw[7];        \
                asm("v_permlane32_swap_b32 %0, %1" : "+v"(c0), "+v"(d0));       \
                asm("v_permlane32_swap_b32 %0, %1" : "+v"(c1), "+v"(d1));       \
                u32x4 fr1 = {c0, c1, d0, d1};                                   \
                pf1 = __builtin_bit_cast(bf16x8, fr1);                          \
            }                                                                   \
        }

#define BODY(jj)                                                                \
    {                                                                           \
        const int kv0 = 64 * (p + 2 * (jj));                                    \
        asm volatile("s_waitcnt vmcnt(4)" ::: "memory");                        \
        __builtin_amdgcn_s_barrier();                                           \
        __builtin_amdgcn_sched_barrier(0);                                      \
        const char* kb = smem + ((jj) & 1) * 16384;                             \
        const char* vb = kb + 8192;                                             \
        const char* krw = kb + (32 * half + ql) * 128;                          \
        bf16x8 kf0 = *(const bf16x8*)(krw + ((0 * 32 + h * 16) ^ swz));         \
        bf16x8 kf1 = *(const bf16x8*)(krw + ((1 * 32 + h * 16) ^ swz));         \
        bf16x8 kf2 = *(const bf16x8*)(krw + ((2 * 32 + h * 16) ^ swz));         \
        bf16x8 kf3 = *(const bf16x8*)(krw + ((3 * 32 + h * 16) ^ swz));         \
        const char* vr0 = vb + ql * 128;                                        \
        const char* vr1 = vb + (32 + ql) * 128;                                 \
        int vc0 = (64 * half + 16 * h) ^ swz;                                   \
        int vc1 = (64 * half + 32 + 16 * h) ^ swz;                              \
        bf16x8 vf00 = *(const bf16x8*)(vr0 + vc0);                              \
        bf16x8 vf01 = *(const bf16x8*)(vr0 + vc1);                              \
        bf16x8 vf10 = *(const bf16x8*)(vr1 + vc0);                              \
        bf16x8 vf11 = *(const bf16x8*)(vr1 + vc1);                              \
        asm volatile("s_waitcnt lgkmcnt(0)" ::: "memory");                      \
        __builtin_amdgcn_sched_barrier(0);                                      \
        __builtin_amdgcn_s_barrier();                                           \
        __builtin_amdgcn_sched_barrier(0);                                      \
        { int kst = ((jj) + 2 < nb) ? kv0 + 256 : kv0; STAGE((jj) & 1, kst); }  \
        bool act = (kv0 + 32 * half <= t0 + 31);                                \
        bf16x8 pf0, pf1;                                                        \
        __builtin_amdgcn_s_setprio(1);                                          \
        if (act) QK_SM(pf0, pf1)                                                \
        if (act) {                                                              \
            acc0 = __builtin_amdgcn_mfma_f32_32x32x16_bf16(vf00, pf0, acc0, 0, 0, 0); \
            acc0 = __builtin_amdgcn_mfma_f32_32x32x16_bf16(vf01, pf1, acc0, 0, 0, 0); \
            acc1 = __builtin_amdgcn_mfma_f32_32x32x16_bf16(vf10, pf0, acc1, 0, 0, 0); \
            acc1 = __builtin_amdgcn_mfma_f32_32x32x16_bf16(vf11, pf1, acc1, 0, 0, 0); \
        }                                                                       \
        __builtin_amdgcn_s_setprio(0);                                          \
    }

    // Prologue: depth-2 staging (ghost duplicate when nb==1 keeps counts uniform).
    if (nb > 0) {
        STAGE(0, 64 * p);
        int k1 = (nb > 1) ? 64 * p + 128 : 64 * p;
        STAGE(1, k1);
    }

    for (int j = 0; j < nb; ++j) BODY(j);
#undef BODY
#undef QK_SM
#undef STAGE

    // Full drain: in-flight ghost stages must land before smem is reused.
    __syncthreads();

    // ---- combine: 2 partials/tile. half1 publishes, half0 absorbs+writes
    //      UNNORMALIZED partial (acc, l) to this parity's buffers.
    l += __shfl_xor(l, 32);
    float* sg = (float*)smem + tile * 2112 + lane * 33;  // 2 x [64][33] f32
    if (half == 1) {
        #pragma unroll
        for (int g = 0; g < 4; ++g) {
            *(f32x4*)(sg + 4 * g)      = f32x4{acc0[4*g+0], acc0[4*g+1], acc0[4*g+2], acc0[4*g+3]};
            *(f32x4*)(sg + 16 + 4 * g) = f32x4{acc1[4*g+0], acc1[4*g+1], acc1[4*g+2], acc1[4*g+3]};
        }
        sg[32] = l;
    }
    __syncthreads();
    if (half == 0) {
        #pragma unroll
        for (int g = 0; g < 4; ++g) {
            f32x4 u0 = *(f32x4*)(sg + 4 * g);
            f32x4 u1 = *(f32x4*)(sg + 16 + 4 * g);
            acc0[4*g+0] += u0[0]; acc0[4*g+1] += u0[1]; acc0[4*g+2] += u0[2]; acc0[4*g+3] += u0[3];
            acc1[4*g+0] += u1[0]; acc1[4*g+1] += u1[1]; acc1[4*g+2] += u1[2]; acc1[4*g+3] += u1[3];
        }
        l += sg[32];
        int head = bh & 1, bb = bh >> 1;
        float* Pdst = p ? P1 : Hf;
        float* Ldst = p ? L1 : L0;
        float* hp = Pdst + ((size_t)(bb * T_SEQ) + t0 + ql) * 128 + head * 64 + 4 * h;
        #pragma unroll
        for (int g2 = 0; g2 < 4; ++g2) {
            f32x4 s0 = { acc0[g2*4+0], acc0[g2*4+1], acc0[g2*4+2], acc0[g2*4+3] };
            *(f32x4*)(hp + 8 * g2) = s0;               // d = 8*g2+4h+0..3
            f32x4 s1 = { acc1[g2*4+0], acc1[g2*4+1], acc1[g2*4+2], acc1[g2*4+3] };
            *(f32x4*)(hp + 32 + 8 * g2) = s1;          // d = 32+8*g2+4h+0..3
        }
        if (h == 0)                       // one lane per q-row
            Ldst[(size_t)bh * T_SEQ + t0 + ql] = l;
    }
}

// ---------------------------------------------------------------------------
// Kernel 4a: one-shot Wout -> Wt bf16, transposed + xor-swizzled for LDS.
// ---------------------------------------------------------------------------
__global__ __launch_bounds__(256) void prep_wt(
    const float* __restrict__ Wout, short* __restrict__ Wt)
{
    int tid = blockIdx.x * 256 + threadIdx.x;   // 16384
    int j = tid >> 7, k = tid & 127;
    float v = Wout[k * 128 + j];
    int slot = k >> 3;
    Wt[j * 128 + (((slot ^ (j & 7)) << 3) | (k & 7))] = f2bfs(v);
}

// ---------------------------------------------------------------------------
// Kernel 4b: out = ((P0+P1) * 1/(L0+L1)) @ Wout -> f32 (in place over P0).
// Row-block-diagonal: each wave reads only its own 16 rows before writing.
// Normalization folded into the bf16 fragment build (per-head rl).
// ---------------------------------------------------------------------------
__global__ __launch_bounds__(256) void out_proj(
    const float* P0, const float* __restrict__ P1,
    const float* __restrict__ L0, const float* __restrict__ L1,
    const short* __restrict__ Wt, float* out)
{
    __shared__ __align__(16) char lws[32768];
    int tid = threadIdx.x;
    int w = tid >> 6, lane = tid & 63, c = lane & 15, g = lane >> 4;
    int cs = c & 7;
    #pragma unroll
    for (int z = 0; z < 8; ++z)
        __builtin_amdgcn_global_load_lds((gptr_t)(Wt + z * 2048 + w * 512 + lane * 8),
                                         (lptr_t)(lws + z * 4096 + w * 1024), 16, 0, 0);
    __syncthreads();

    int row0 = blockIdx.x * 64 + w * 16;
    int r = row0 + c;
    int b = r >> 12, t = r & (T_SEQ - 1);
    float rl0 = 1.0f / (L0[(size_t)(b * 2 + 0) * T_SEQ + t] + L1[(size_t)(b * 2 + 0) * T_SEQ + t]);
    float rl1 = 1.0f / (L0[(size_t)(b * 2 + 1) * T_SEQ + t] + L1[(size_t)(b * 2 + 1) * T_SEQ + t]);

    bf16x8 af[4];
    const float* hp0 = P0 + (size_t)r * 128 + g * 8;
    const float* hp1 = P1 + (size_t)r * 128 + g * 8;
    #pragma unroll
    for (int kc = 0; kc < 4; ++kc) {
        float rl = (kc < 2) ? rl0 : rl1;          // d = kc*32+g*8+.. ; head = d>>6
        f32x4 x0 = *(const f32x4*)(hp0 + kc * 32);
        f32x4 x1 = *(const f32x4*)(hp0 + kc * 32 + 4);
        f32x4 y0 = *(const f32x4*)(hp1 + kc * 32);
        f32x4 y1 = *(const f32x4*)(hp1 + kc * 32 + 4);
        u32x4 wv = { cvtpk((x0[0]+y0[0])*rl, (x0[1]+y0[1])*rl),
                     cvtpk((x0[2]+y0[2])*rl, (x0[3]+y0[3])*rl),
                     cvtpk((x1[0]+y1[0])*rl, (x1[1]+y1[1])*rl),
                     cvtpk((x1[2]+y1[2])*rl, (x1[3]+y1[3])*rl) };
        af[kc] = __builtin_bit_cast(bf16x8, wv);
    }
    #pragma unroll
    for (int jt = 0; jt < 8; ++jt) {
        f32x4 accum = {0.f, 0.f, 0.f, 0.f};
        #pragma unroll
        for (int kc = 0; kc < 4; ++kc) {
            int row = jt * 16 + c;
            bf16x8 bfr = *(const bf16x8*)(lws + row * 256 + (((kc * 4 + g) ^ cs) << 4));
            accum = __builtin_amdgcn_mfma_f32_16x16x32_bf16(af[kc], bfr, accum, 0, 0, 0);
        }
        #pragma unroll
        for (int rr = 0; rr < 4; ++rr)
            out[(size_t)(row0 + g * 4 + rr) * 128 + jt * 16 + c] = accum[rr];
    }
}

// ---------------------------------------------------------------------------
extern "C" void kernel_launch(void* const* d_in, const int* in_sizes, int n_in,
                              void* d_out, int out_size, void* d_ws, size_t ws_size,
                              hipStream_t stream)
{
    (void)in_sizes; (void)n_in; (void)out_size; (void)ws_size;
    const float* x    = (const float*)d_in[0];
    const float* Wq1  = (const float*)d_in[1];
    const float* Wk1  = (const float*)d_in[2];
    const float* Wv1  = (const float*)d_in[3];
    const float* Wq2  = (const float*)d_in[4];
    const float* Wk2  = (const float*)d_in[5];
    const float* Wv2  = (const float*)d_in[6];
    const float* Wout = (const float*)d_in[7];
    float* out = (float*)d_out;

    char* ws = (char*)d_ws;
    short* Q  = (short*)(ws);                               // 8 MiB (dead after attn)
    short* K  = (short*)(ws + (size_t)8  * 1024 * 1024);    // 8 MiB
    short* Vt = (short*)(ws + (size_t)16 * 1024 * 1024);    // 8 MiB
    float* P1 = (float*)(ws + (size_t)24 * 1024 * 1024);    // 16 MiB partial
    float* L0 = (float*)(ws + (size_t)40 * 1024 * 1024);    // 256 KiB
    float* L1 = (float*)(ws + (size_t)40 * 1024 * 1024 + 262144);
    short* Wt = Q;                                          // reuse Q region
    float* Hf = out;                                        // P0 lives in d_out

    qk_proj <<<8192, 256, 0, stream>>>(x, Wq1, Wk1, Wq2, Wk2, Q, K);
    v_proj_t<<<1024, 256, 0, stream>>>(x, Wv1, Wv2, Vt);
    attn    <<<2048, 256, 0, stream>>>(Q, K, Vt, Hf, P1, L0, L1);
    prep_wt <<<  64, 256, 0, stream>>>(Wout, Wt);
    out_proj<<< 512, 256, 0, stream>>>(Hf, P1, L0, L1, Wt, out);
}

// Round 12
// 86.478 us; speedup vs baseline: 1.7415x; 1.0464x over previous
//
#include <hip/hip_runtime.h>
#include <hip/hip_bf16.h>
#include <stdint.h>

#define T_SEQ 4096

typedef float  f32x4   __attribute__((ext_vector_type(4)));
typedef float  f32x16  __attribute__((ext_vector_type(16)));
typedef short  bf16x8  __attribute__((ext_vector_type(8)));
typedef short  s16x4   __attribute__((ext_vector_type(4)));
typedef unsigned int u32x4 __attribute__((ext_vector_type(4)));

typedef const __attribute__((address_space(1))) uint32_t* gptr_t;
typedef __attribute__((address_space(3))) uint32_t* lptr_t;

__device__ __forceinline__ uint32_t f2bf1(float f) {
    uint32_t u = __float_as_uint(f);
    return (u + 0x7fffu + ((u >> 16) & 1u)) >> 16;   // RNE f32->bf16
}
__device__ __forceinline__ short f2bfs(float f) { return (short)f2bf1(f); }
__device__ __forceinline__ uint32_t cvtpk(float lo, float hi) {
    uint32_t r;
    asm("v_cvt_pk_bf16_f32 %0, %1, %2" : "=v"(r) : "v"(lo), "v"(hi));
    return r;
}

// ---------------------------------------------------------------------------
// Kernel 1: Q,K projections, 4 d-values per thread, short4 stores.
//   R12: old version was store-instruction-bound (4 scalar 2B stores/thread,
//   128B/wave segments). Now: thread owns (b, t, d-quad); each wave's store
//   instruction covers 512B contiguous (16 d-quads x 4 consecutive t).
//   Grid 8192 -> 2048. Math identical (Q pre-scaled by 0.125*log2e).
//   Layout: [bh=b*2+h][t][64] bf16.
// ---------------------------------------------------------------------------
__global__ __launch_bounds__(256) void qk_proj(
    const float* __restrict__ x,
    const float* __restrict__ Wq1, const float* __restrict__ Wk1,
    const float* __restrict__ Wq2, const float* __restrict__ Wk2,
    short* __restrict__ Q, short* __restrict__ K)
{
    int idx = blockIdx.x * 256 + threadIdx.x;   // 524288 = 16 dq x 4096 t x 8 b
    int d0 = (idx & 15) * 4;
    int t = (idx >> 4) & (T_SEQ - 1);
    int b = idx >> 16;
    const float* xp = x + (size_t)(b * T_SEQ + t) * 6;
    float x0 = xp[0], x1 = xp[1], x2 = xp[2];
    float x3 = xp[3], x4 = xp[4], x5 = xp[5];
    const float QS = 0.125f * 1.44269504088896340736f;
    s16x4 vq1, vk1, vq2, vk2;
    #pragma unroll
    for (int j = 0; j < 4; ++j) {
        int d = d0 + j;
        float q1 = (x0 * Wq1[d] + x1 * Wq1[64 + d] + x2 * Wq1[128 + d]) * QS;
        float k1 =  x0 * Wk1[d] + x1 * Wk1[64 + d] + x2 * Wk1[128 + d];
        float q2 = (x3 * Wq2[d] + x4 * Wq2[64 + d] + x5 * Wq2[128 + d]) * QS;
        float k2 =  x3 * Wk2[d] + x4 * Wk2[64 + d] + x5 * Wk2[128 + d];
        vq1[j] = f2bfs(q1);  vk1[j] = f2bfs(k1);
        vq2[j] = f2bfs(q2);  vk2[j] = f2bfs(k2);
    }
    size_t base1 = ((size_t)(b * 2 + 0) * T_SEQ + t) * 64 + d0;
    size_t base2 = ((size_t)(b * 2 + 1) * T_SEQ + t) * 64 + d0;
    *(s16x4*)(Q + base1) = vq1;  *(s16x4*)(Q + base2) = vq2;
    *(s16x4*)(K + base1) = vk1;  *(s16x4*)(K + base2) = vk2;
}

// ---------------------------------------------------------------------------
// Kernel 2: V projection TRANSPOSED Vt[bh][d][t] bf16, 2 t-values per thread
//   packed into one u32 store (256B contiguous per wave store instr; was
//   128B scalar). Grid 1024 -> 512. Math identical.
// ---------------------------------------------------------------------------
__global__ __launch_bounds__(256) void v_proj_t(
    const float* __restrict__ x,
    const float* __restrict__ Wv1, const float* __restrict__ Wv2,
    short* __restrict__ Vt)
{
    int bh = blockIdx.x >> 5;            // 0..15
    int tt = blockIdx.x & 31;            // 0..31 (128 t per block)
    int head = bh & 1, b = bh >> 1;
    int t  = tt * 128 + 2 * (threadIdx.x & 63);
    int dg = threadIdx.x >> 6;
    const float* Wv = head ? Wv2 : Wv1;
    const float* xp = x + (size_t)(b * T_SEQ + t) * 6 + head * 3;
    float xa0 = xp[0], xa1 = xp[1], xa2 = xp[2];
    float xb0 = xp[6], xb1 = xp[7], xb2 = xp[8];
    size_t base = (size_t)bh * 64 * T_SEQ + t;
    #pragma unroll
    for (int k = 0; k < 16; ++k) {
        int d = dg * 16 + k;
        float va = xa0 * Wv[d] + xa1 * Wv[64 + d] + xa2 * Wv[128 + d];
        float vb = xb0 * Wv[d] + xb1 * Wv[64 + d] + xb2 * Wv[128 + d];
        uint32_t pk = f2bf1(va) | (f2bf1(vb) << 16);
        *(uint32_t*)(Vt + base + (size_t)d * T_SEQ) = pk;
    }
}

// ---------------------------------------------------------------------------
// Kernel 3: causal flash attention, (tile, kv-half) waves + KV-SPLIT blocks.
//   R12: VERBATIM R8 (session-best: attn 65.2us, total 89.1). R9/R10/R11
//   variants (fold-sharing, V-in-regs, counted-vmcnt barriers) all null or
//   negative -- this wave-level structure sits at a distributed latency/sync
//   equilibrium (no pipe >50%, body-slot ~1200cy vs ~600cy chain).
//   Block (s, p): pair s (tiles 64s, 64s+32), chunks c = p, p+2, ... < s+1
//   -> <= 32 bodies; static-max softmax => partials additive: emits
//   UNNORMALIZED acc and l. p=0 -> Hf+L0; p=1 -> P1+L1. out_proj combines.
// ---------------------------------------------------------------------------
__global__ __launch_bounds__(256, 4) void attn(
    const short* __restrict__ Q, const short* __restrict__ K,
    const short* __restrict__ Vt, float* __restrict__ Hf,
    float* __restrict__ P1, float* __restrict__ L0, float* __restrict__ L1)
{
    __shared__ __align__(16) char smem[32768];  // dbuf 2 x (K 8K + V 8K)

    int id = blockIdx.x;                 // 2048
    int xcd = id & 7, rest = id >> 3;    // rest 0..255
    int bh = xcd * 2 + (rest & 1);       // 2 bh per XCD (L2 locality)
    int rem = rest >> 1;                 // 0..127
    int s  = 63 - (rem >> 1);            // pair index, LONGEST FIRST
    int p  = rem & 1;                    // kv-parity half
    int tid = threadIdx.x;
    int W = tid >> 6;
    int lane = tid & 63;
    int ql = lane & 31, h = lane >> 5;
    int tile = W >> 1, half = W & 1;     // wave's (tile, kv-half)
    int t0 = 64 * s + 32 * tile;
    int q  = t0 + ql;
    int n  = s + 1;                      // total 64-kv chunks for this pair
    int nb = (n - p + 1) >> 1;           // my chunk count: ceil((n-p)/2)

    size_t kvbase = (size_t)bh * (T_SEQ * 64);

    // Q fragment (B-operand): lane holds Q[q][ks*16 + h*8 + j]
    bf16x8 qf[4];
    #pragma unroll
    for (int ks = 0; ks < 4; ++ks)
        qf[ks] = *(const bf16x8*)(Q + kvbase + (size_t)q * 64 + ks * 16 + h * 8);

    // staging maps (256 threads): row = tid>>3 (0..31), slot = tid&7,
    // pre-swizzled source column; LDS dest linear (swizzle applied on read).
    int krl = tid >> 3;
    int kcol = ((tid & 7) ^ (krl & 7)) * 8;
    const short* ksrc0 = K + kvbase + kcol;              // + srow*64
    const short* vsrc0 = Vt + kvbase + kcol;             // + d*T_SEQ + kv

    f32x16 acc0, acc1;
    #pragma unroll
    for (int rr = 0; rr < 16; ++rr) { acc0[rr] = 0.f; acc1[rr] = 0.f; }
    float l = 0.f;
    int swz = (ql & 7) << 4;

#define STAGE(bsel, kvv)                                                        \
    {                                                                           \
        char* kb = smem + (bsel) * 16384;                                       \
        char* vb = kb + 8192;                                                   \
        _Pragma("unroll")                                                       \
        for (int z = 0; z < 2; ++z)                                             \
            __builtin_amdgcn_global_load_lds(                                   \
                (gptr_t)(ksrc0 + (size_t)((kvv) + 32 * z + krl) * 64),          \
                (lptr_t)(kb + z * 4096 + tid * 16), 16, 0, 0);                  \
        _Pragma("unroll")                                                       \
        for (int z = 0; z < 2; ++z)                                             \
            __builtin_amdgcn_global_load_lds(                                   \
                (gptr_t)(vsrc0 + (size_t)(32 * z + krl) * T_SEQ + (kvv)),       \
                (lptr_t)(vb + z * 4096 + tid * 16), 16, 0, 0);                  \
    }

#define QK_SM(pf0, pf1)                                                         \
        {                                                                       \
            f32x16 Sv;                                                          \
            _Pragma("unroll") for (int rr = 0; rr < 16; ++rr) Sv[rr] = 0.f;     \
            Sv = __builtin_amdgcn_mfma_f32_32x32x16_bf16(kf0, qf[0], Sv,0,0,0); \
            Sv = __builtin_amdgcn_mfma_f32_32x32x16_bf16(kf1, qf[1], Sv,0,0,0); \
            Sv = __builtin_amdgcn_mfma_f32_32x32x16_bf16(kf2, qf[2], Sv,0,0,0); \
            Sv = __builtin_amdgcn_mfma_f32_32x32x16_bf16(kf3, qf[3], Sv,0,0,0); \
            bool needmask = (kv0 + 32 * half + 31 > t0);  /* max_kv > t0 */     \
            uint32_t pw[8];                                                     \
            float l0 = 0.f, l1 = 0.f;                                           \
            _Pragma("unroll") for (int e = 0; e < 8; ++e) {                     \
                float p0 = __builtin_amdgcn_exp2f(Sv[2 * e]);                   \
                float p1 = __builtin_amdgcn_exp2f(Sv[2 * e + 1]);               \
                if (needmask) {                                                 \
                    int kv = kv0 + 32 * half + 4 * h + 2 * (e & 1) + 8 * (e >> 1); \
                    p0 = (kv     <= q) ? p0 : 0.f;                              \
                    p1 = (kv + 1 <= q) ? p1 : 0.f;                              \
                }                                                               \
                l0 += p0; l1 += p1;                                             \
                pw[e] = cvtpk(p0, p1);                                          \
            }                                                                   \
            l += l0 + l1;                                                       \
            {                                                                   \
                uint32_t a0 = pw[0], b0 = pw[2], a1 = pw[1], b1 = pw[3];        \
                asm("v_permlane32_swap_b32 %0, %1" : "+v"(a0), "+v"(b0));       \
                asm("v_permlane32_swap_b32 %0, %1" : "+v"(a1), "+v"(b1));       \
                u32x4 fr = {a0, a1, b0, b1};                                    \
                pf0 = __builtin_bit_cast(bf16x8, fr);                           \
                uint32_t c0 = pw[4], d0 = pw[6], c1 = pw[5], d1 = pw[7];        \
                asm("v_permlane32_swap_b32 %0, %1" : "+v"(c0), "+v"(d0));       \
                asm("v_permlane32_swap_b32 %0, %1" : "+v"(c1), "+v"(d1));       \
                u32x4 fr1 = {c0, c1, d0, d1};                                   \
                pf1 = __builtin_bit_cast(bf16x8, fr1);                          \
            }                                                                   \
        }

#define BODY(jj)                                                                \
    {                                                                           \
        const int kv0 = 64 * (p + 2 * (jj));                                    \
        if ((jj) + 1 < nb) STAGE(((jj) + 1) & 1, kv0 + 128);                    \
        const char* kb = smem + ((jj) & 1) * 16384;                             \
        const char* vb = kb + 8192;                                             \
        const char* krw = kb + (32 * half + ql) * 128;                          \
        bf16x8 kf0 = *(const bf16x8*)(krw + ((0 * 32 + h * 16) ^ swz));         \
        bf16x8 kf1 = *(const bf16x8*)(krw + ((1 * 32 + h * 16) ^ swz));         \
        bf16x8 kf2 = *(const bf16x8*)(krw + ((2 * 32 + h * 16) ^ swz));         \
        bf16x8 kf3 = *(const bf16x8*)(krw + ((3 * 32 + h * 16) ^ swz));         \
        bool act = (kv0 + 32 * half <= t0 + 31);                                \
        bf16x8 pf0, pf1;                                                        \
        __builtin_amdgcn_s_setprio(1);                                          \
        if (act) QK_SM(pf0, pf1)                                                \
        const char* vr0 = vb + ql * 128;                                        \
        const char* vr1 = vb + (32 + ql) * 128;                                 \
        int vc0 = (64 * half + 16 * h) ^ swz;                                   \
        int vc1 = (64 * half + 32 + 16 * h) ^ swz;                              \
        bf16x8 vf00 = *(const bf16x8*)(vr0 + vc0);                              \
        bf16x8 vf01 = *(const bf16x8*)(vr0 + vc1);                              \
        bf16x8 vf10 = *(const bf16x8*)(vr1 + vc0);                              \
        bf16x8 vf11 = *(const bf16x8*)(vr1 + vc1);                              \
        if (act) {                                                              \
            acc0 = __builtin_amdgcn_mfma_f32_32x32x16_bf16(vf00, pf0, acc0, 0, 0, 0); \
            acc0 = __builtin_amdgcn_mfma_f32_32x32x16_bf16(vf01, pf1, acc0, 0, 0, 0); \
            acc1 = __builtin_amdgcn_mfma_f32_32x32x16_bf16(vf10, pf0, acc1, 0, 0, 0); \
            acc1 = __builtin_amdgcn_mfma_f32_32x32x16_bf16(vf11, pf1, acc1, 0, 0, 0); \
        }                                                                       \
        __builtin_amdgcn_s_setprio(0);                                          \
        __syncthreads();                                                        \
    }

    if (nb > 0) STAGE(0, 64 * p);        // prologue: first chunk -> buf 0
    __syncthreads();

    for (int j = 0; j < nb; ++j) BODY(j);
#undef BODY
#undef QK_SM
#undef STAGE

    // ---- combine: 2 partials/tile. half1 publishes, half0 absorbs+writes
    //      UNNORMALIZED partial (acc, l) to this parity's buffers.
    l += __shfl_xor(l, 32);
    float* sg = (float*)smem + tile * 2112 + lane * 33;  // 2 x [64][33] f32
    if (half == 1) {
        #pragma unroll
        for (int g = 0; g < 4; ++g) {
            *(f32x4*)(sg + 4 * g)      = f32x4{acc0[4*g+0], acc0[4*g+1], acc0[4*g+2], acc0[4*g+3]};
            *(f32x4*)(sg + 16 + 4 * g) = f32x4{acc1[4*g+0], acc1[4*g+1], acc1[4*g+2], acc1[4*g+3]};
        }
        sg[32] = l;
    }
    __syncthreads();
    if (half == 0) {
        #pragma unroll
        for (int g = 0; g < 4; ++g) {
            f32x4 u0 = *(f32x4*)(sg + 4 * g);
            f32x4 u1 = *(f32x4*)(sg + 16 + 4 * g);
            acc0[4*g+0] += u0[0]; acc0[4*g+1] += u0[1]; acc0[4*g+2] += u0[2]; acc0[4*g+3] += u0[3];
            acc1[4*g+0] += u1[0]; acc1[4*g+1] += u1[1]; acc1[4*g+2] += u1[2]; acc1[4*g+3] += u1[3];
        }
        l += sg[32];
        int head = bh & 1, bb = bh >> 1;
        float* Pdst = p ? P1 : Hf;
        float* Ldst = p ? L1 : L0;
        float* hp = Pdst + ((size_t)(bb * T_SEQ) + t0 + ql) * 128 + head * 64 + 4 * h;
        #pragma unroll
        for (int g2 = 0; g2 < 4; ++g2) {
            f32x4 s0 = { acc0[g2*4+0], acc0[g2*4+1], acc0[g2*4+2], acc0[g2*4+3] };
            *(f32x4*)(hp + 8 * g2) = s0;               // d = 8*g2+4h+0..3
            f32x4 s1 = { acc1[g2*4+0], acc1[g2*4+1], acc1[g2*4+2], acc1[g2*4+3] };
            *(f32x4*)(hp + 32 + 8 * g2) = s1;          // d = 32+8*g2+4h+0..3
        }
        if (h == 0)                       // one lane per q-row
            Ldst[(size_t)bh * T_SEQ + t0 + ql] = l;
    }
}

// ---------------------------------------------------------------------------
// Kernel 4a: one-shot Wout -> Wt bf16, transposed + xor-swizzled for LDS.
// ---------------------------------------------------------------------------
__global__ __launch_bounds__(256) void prep_wt(
    const float* __restrict__ Wout, short* __restrict__ Wt)
{
    int tid = blockIdx.x * 256 + threadIdx.x;   // 16384
    int j = tid >> 7, k = tid & 127;
    float v = Wout[k * 128 + j];
    int slot = k >> 3;
    Wt[j * 128 + (((slot ^ (j & 7)) << 3) | (k & 7))] = f2bfs(v);
}

// ---------------------------------------------------------------------------
// Kernel 4b: out = ((P0+P1) * 1/(L0+L1)) @ Wout -> f32 (in place over P0).
// Row-block-diagonal: each wave reads only its own 16 rows before writing.
// Normalization folded into the bf16 fragment build (per-head rl).
// ---------------------------------------------------------------------------
__global__ __launch_bounds__(256) void out_proj(
    const float* P0, const float* __restrict__ P1,
    const float* __restrict__ L0, const float* __restrict__ L1,
    const short* __restrict__ Wt, float* out)
{
    __shared__ __align__(16) char lws[32768];
    int tid = threadIdx.x;
    int w = tid >> 6, lane = tid & 63, c = lane & 15, g = lane >> 4;
    int cs = c & 7;
    #pragma unroll
    for (int z = 0; z < 8; ++z)
        __builtin_amdgcn_global_load_lds((gptr_t)(Wt + z * 2048 + w * 512 + lane * 8),
                                         (lptr_t)(lws + z * 4096 + w * 1024), 16, 0, 0);
    __syncthreads();

    int row0 = blockIdx.x * 64 + w * 16;
    int r = row0 + c;
    int b = r >> 12, t = r & (T_SEQ - 1);
    float rl0 = 1.0f / (L0[(size_t)(b * 2 + 0) * T_SEQ + t] + L1[(size_t)(b * 2 + 0) * T_SEQ + t]);
    float rl1 = 1.0f / (L0[(size_t)(b * 2 + 1) * T_SEQ + t] + L1[(size_t)(b * 2 + 1) * T_SEQ + t]);

    bf16x8 af[4];
    const float* hp0 = P0 + (size_t)r * 128 + g * 8;
    const float* hp1 = P1 + (size_t)r * 128 + g * 8;
    #pragma unroll
    for (int kc = 0; kc < 4; ++kc) {
        float rl = (kc < 2) ? rl0 : rl1;          // d = kc*32+g*8+.. ; head = d>>6
        f32x4 x0 = *(const f32x4*)(hp0 + kc * 32);
        f32x4 x1 = *(const f32x4*)(hp0 + kc * 32 + 4);
        f32x4 y0 = *(const f32x4*)(hp1 + kc * 32);
        f32x4 y1 = *(const f32x4*)(hp1 + kc * 32 + 4);
        u32x4 wv = { cvtpk((x0[0]+y0[0])*rl, (x0[1]+y0[1])*rl),
                     cvtpk((x0[2]+y0[2])*rl, (x0[3]+y0[3])*rl),
                     cvtpk((x1[0]+y1[0])*rl, (x1[1]+y1[1])*rl),
                     cvtpk((x1[2]+y1[2])*rl, (x1[3]+y1[3])*rl) };
        af[kc] = __builtin_bit_cast(bf16x8, wv);
    }
    #pragma unroll
    for (int jt = 0; jt < 8; ++jt) {
        f32x4 accum = {0.f, 0.f, 0.f, 0.f};
        #pragma unroll
        for (int kc = 0; kc < 4; ++kc) {
            int row = jt * 16 + c;
            bf16x8 bfr = *(const bf16x8*)(lws + row * 256 + (((kc * 4 + g) ^ cs) << 4));
            accum = __builtin_amdgcn_mfma_f32_16x16x32_bf16(af[kc], bfr, accum, 0, 0, 0);
        }
        #pragma unroll
        for (int rr = 0; rr < 4; ++rr)
            out[(size_t)(row0 + g * 4 + rr) * 128 + jt * 16 + c] = accum[rr];
    }
}

// ---------------------------------------------------------------------------
extern "C" void kernel_launch(void* const* d_in, const int* in_sizes, int n_in,
                              void* d_out, int out_size, void* d_ws, size_t ws_size,
                              hipStream_t stream)
{
    (void)in_sizes; (void)n_in; (void)out_size; (void)ws_size;
    const float* x    = (const float*)d_in[0];
    const float* Wq1  = (const float*)d_in[1];
    const float* Wk1  = (const float*)d_in[2];
    const float* Wv1  = (const float*)d_in[3];
    const float* Wq2  = (const float*)d_in[4];
    const float* Wk2  = (const float*)d_in[5];
    const float* Wv2  = (const float*)d_in[6];
    const float* Wout = (const float*)d_in[7];
    float* out = (float*)d_out;

    char* ws = (char*)d_ws;
    short* Q  = (short*)(ws);                               // 8 MiB (dead after attn)
    short* K  = (short*)(ws + (size_t)8  * 1024 * 1024);    // 8 MiB
    short* Vt = (short*)(ws + (size_t)16 * 1024 * 1024);    // 8 MiB
    float* P1 = (float*)(ws + (size_t)24 * 1024 * 1024);    // 16 MiB partial
    float* L0 = (float*)(ws + (size_t)40 * 1024 * 1024);    // 256 KiB
    float* L1 = (float*)(ws + (size_t)40 * 1024 * 1024 + 262144);
    short* Wt = Q;                                          // reuse Q region
    float* Hf = out;                                        // P0 lives in d_out

    qk_proj <<<2048, 256, 0, stream>>>(x, Wq1, Wk1, Wq2, Wk2, Q, K);
    v_proj_t<<< 512, 256, 0, stream>>>(x, Wv1, Wv2, Vt);
    attn    <<<2048, 256, 0, stream>>>(Q, K, Vt, Hf, P1, L0, L1);
    prep_wt <<<  64, 256, 0, stream>>>(Wout, Wt);
    out_proj<<< 512, 256, 0, stream>>>(Hf, P1, L0, L1, Wt, out);
}

// Round 13
// 82.253 us; speedup vs baseline: 1.8309x; 1.0514x over previous
//
#include <hip/hip_runtime.h>
#include <hip/hip_bf16.h>
#include <stdint.h>

#define T_SEQ 4096

typedef float  f32x4   __attribute__((ext_vector_type(4)));
typedef float  f32x16  __attribute__((ext_vector_type(16)));
typedef short  bf16x8  __attribute__((ext_vector_type(8)));
typedef short  s16x4   __attribute__((ext_vector_type(4)));
typedef unsigned int u32x4 __attribute__((ext_vector_type(4)));

typedef const __attribute__((address_space(1))) uint32_t* gptr_t;
typedef __attribute__((address_space(3))) uint32_t* lptr_t;

__device__ __forceinline__ uint32_t f2bf1(float f) {
    uint32_t u = __float_as_uint(f);
    return (u + 0x7fffu + ((u >> 16) & 1u)) >> 16;   // RNE f32->bf16
}
__device__ __forceinline__ short f2bfs(float f) { return (short)f2bf1(f); }
__device__ __forceinline__ uint32_t cvtpk(float lo, float hi) {
    uint32_t r;
    asm("v_cvt_pk_bf16_f32 %0, %1, %2" : "=v"(r) : "v"(lo), "v"(hi));
    return r;
}

// ---------------------------------------------------------------------------
// Kernel 1 (MERGED): all pre-attn prep in ONE launch (R13: removes 2 launch
// gaps; the 64 prep-blocks hide inside the projection wave).
//   blocks [0, 2048):    Q,K projections (R12 body: 4 d/thread, short4 stores)
//   blocks [2048, 2560): V projection transposed (R12 body: 2 t/thread, u32)
//   blocks [2560, 2624): Wout -> Wt bf16 transpose+swizzle (Wt NO LONGER
//                        aliases Q -- own ws slot, since prep now runs first)
// ---------------------------------------------------------------------------
__global__ __launch_bounds__(256) void proj_all(
    const float* __restrict__ x,
    const float* __restrict__ Wq1, const float* __restrict__ Wk1,
    const float* __restrict__ Wq2, const float* __restrict__ Wk2,
    const float* __restrict__ Wv1, const float* __restrict__ Wv2,
    const float* __restrict__ Wout,
    short* __restrict__ Q, short* __restrict__ K,
    short* __restrict__ Vt, short* __restrict__ Wt)
{
    int bid = blockIdx.x;
    if (bid < 2048) {
        // ---- Q,K projection: thread owns (b, t, d-quad) ----
        int idx = bid * 256 + threadIdx.x;      // 524288 = 16 dq x 4096 t x 8 b
        int d0 = (idx & 15) * 4;
        int t = (idx >> 4) & (T_SEQ - 1);
        int b = idx >> 16;
        const float* xp = x + (size_t)(b * T_SEQ + t) * 6;
        float x0 = xp[0], x1 = xp[1], x2 = xp[2];
        float x3 = xp[3], x4 = xp[4], x5 = xp[5];
        const float QS = 0.125f * 1.44269504088896340736f;
        s16x4 vq1, vk1, vq2, vk2;
        #pragma unroll
        for (int j = 0; j < 4; ++j) {
            int d = d0 + j;
            float q1 = (x0 * Wq1[d] + x1 * Wq1[64 + d] + x2 * Wq1[128 + d]) * QS;
            float k1 =  x0 * Wk1[d] + x1 * Wk1[64 + d] + x2 * Wk1[128 + d];
            float q2 = (x3 * Wq2[d] + x4 * Wq2[64 + d] + x5 * Wq2[128 + d]) * QS;
            float k2 =  x3 * Wk2[d] + x4 * Wk2[64 + d] + x5 * Wk2[128 + d];
            vq1[j] = f2bfs(q1);  vk1[j] = f2bfs(k1);
            vq2[j] = f2bfs(q2);  vk2[j] = f2bfs(k2);
        }
        size_t base1 = ((size_t)(b * 2 + 0) * T_SEQ + t) * 64 + d0;
        size_t base2 = ((size_t)(b * 2 + 1) * T_SEQ + t) * 64 + d0;
        *(s16x4*)(Q + base1) = vq1;  *(s16x4*)(Q + base2) = vq2;
        *(s16x4*)(K + base1) = vk1;  *(s16x4*)(K + base2) = vk2;
    } else if (bid < 2560) {
        // ---- V projection transposed: Vt[bh][d][t], 2 t per thread ----
        int vb = bid - 2048;
        int bh = vb >> 5;                // 0..15
        int tt = vb & 31;                // 128 t per block
        int head = bh & 1, b = bh >> 1;
        int t  = tt * 128 + 2 * (threadIdx.x & 63);
        int dg = threadIdx.x >> 6;
        const float* Wv = head ? Wv2 : Wv1;
        const float* xp = x + (size_t)(b * T_SEQ + t) * 6 + head * 3;
        float xa0 = xp[0], xa1 = xp[1], xa2 = xp[2];
        float xb0 = xp[6], xb1 = xp[7], xb2 = xp[8];
        size_t base = (size_t)bh * 64 * T_SEQ + t;
        #pragma unroll
        for (int k = 0; k < 16; ++k) {
            int d = dg * 16 + k;
            float va = xa0 * Wv[d] + xa1 * Wv[64 + d] + xa2 * Wv[128 + d];
            float vb2 = xb0 * Wv[d] + xb1 * Wv[64 + d] + xb2 * Wv[128 + d];
            uint32_t pk = f2bf1(va) | (f2bf1(vb2) << 16);
            *(uint32_t*)(Vt + base + (size_t)d * T_SEQ) = pk;
        }
    } else {
        // ---- Wout -> Wt bf16, transposed + xor-swizzled ----
        int tid = (bid - 2560) * 256 + threadIdx.x;   // 16384
        int j = tid >> 7, k = tid & 127;
        float v = Wout[k * 128 + j];
        int slot = k >> 3;
        Wt[j * 128 + (((slot ^ (j & 7)) << 3) | (k & 7))] = f2bfs(v);
    }
}

// ---------------------------------------------------------------------------
// Kernel 2: causal flash attention, (tile, kv-half) waves + KV-SPLIT blocks.
//   VERBATIM R8/R12 (session-best attn: 65.9us). Five structural variants
//   (R9 fold, R10 V-in-regs, R11 counted-vmcnt, R7 occupancy, R5 balance)
//   all null/negative: this wave-level structure sits at a distributed
//   latency/sync equilibrium (no pipe >50%).
//   Block (s, p): pair s (tiles 64s, 64s+32), chunks c = p, p+2, ... < s+1
//   -> <= 32 bodies; static-max softmax => partials additive: emits
//   UNNORMALIZED acc and l. p=0 -> Hf+L0; p=1 -> P1+L1. out_proj combines.
// ---------------------------------------------------------------------------
__global__ __launch_bounds__(256, 4) void attn(
    const short* __restrict__ Q, const short* __restrict__ K,
    const short* __restrict__ Vt, float* __restrict__ Hf,
    float* __restrict__ P1, float* __restrict__ L0, float* __restrict__ L1)
{
    __shared__ __align__(16) char smem[32768];  // dbuf 2 x (K 8K + V 8K)

    int id = blockIdx.x;                 // 2048
    int xcd = id & 7, rest = id >> 3;    // rest 0..255
    int bh = xcd * 2 + (rest & 1);       // 2 bh per XCD (L2 locality)
    int rem = rest >> 1;                 // 0..127
    int s  = 63 - (rem >> 1);            // pair index, LONGEST FIRST
    int p  = rem & 1;                    // kv-parity half
    int tid = threadIdx.x;
    int W = tid >> 6;
    int lane = tid & 63;
    int ql = lane & 31, h = lane >> 5;
    int tile = W >> 1, half = W & 1;     // wave's (tile, kv-half)
    int t0 = 64 * s + 32 * tile;
    int q  = t0 + ql;
    int n  = s + 1;                      // total 64-kv chunks for this pair
    int nb = (n - p + 1) >> 1;           // my chunk count: ceil((n-p)/2)

    size_t kvbase = (size_t)bh * (T_SEQ * 64);

    // Q fragment (B-operand): lane holds Q[q][ks*16 + h*8 + j]
    bf16x8 qf[4];
    #pragma unroll
    for (int ks = 0; ks < 4; ++ks)
        qf[ks] = *(const bf16x8*)(Q + kvbase + (size_t)q * 64 + ks * 16 + h * 8);

    // staging maps (256 threads): row = tid>>3 (0..31), slot = tid&7,
    // pre-swizzled source column; LDS dest linear (swizzle applied on read).
    int krl = tid >> 3;
    int kcol = ((tid & 7) ^ (krl & 7)) * 8;
    const short* ksrc0 = K + kvbase + kcol;              // + srow*64
    const short* vsrc0 = Vt + kvbase + kcol;             // + d*T_SEQ + kv

    f32x16 acc0, acc1;
    #pragma unroll
    for (int rr = 0; rr < 16; ++rr) { acc0[rr] = 0.f; acc1[rr] = 0.f; }
    float l = 0.f;
    int swz = (ql & 7) << 4;

#define STAGE(bsel, kvv)                                                        \
    {                                                                           \
        char* kb = smem + (bsel) * 16384;                                       \
        char* vb = kb + 8192;                                                   \
        _Pragma("unroll")                                                       \
        for (int z = 0; z < 2; ++z)                                             \
            __builtin_amdgcn_global_load_lds(                                   \
                (gptr_t)(ksrc0 + (size_t)((kvv) + 32 * z + krl) * 64),          \
                (lptr_t)(kb + z * 4096 + tid * 16), 16, 0, 0);                  \
        _Pragma("unroll")                                                       \
        for (int z = 0; z < 2; ++z)                                             \
            __builtin_amdgcn_global_load_lds(                                   \
                (gptr_t)(vsrc0 + (size_t)(32 * z + krl) * T_SEQ + (kvv)),       \
                (lptr_t)(vb + z * 4096 + tid * 16), 16, 0, 0);                  \
    }

#define QK_SM(pf0, pf1)                                                         \
        {                                                                       \
            f32x16 Sv;                                                          \
            _Pragma("unroll") for (int rr = 0; rr < 16; ++rr) Sv[rr] = 0.f;     \
            Sv = __builtin_amdgcn_mfma_f32_32x32x16_bf16(kf0, qf[0], Sv,0,0,0); \
            Sv = __builtin_amdgcn_mfma_f32_32x32x16_bf16(kf1, qf[1], Sv,0,0,0); \
            Sv = __builtin_amdgcn_mfma_f32_32x32x16_bf16(kf2, qf[2], Sv,0,0,0); \
            Sv = __builtin_amdgcn_mfma_f32_32x32x16_bf16(kf3, qf[3], Sv,0,0,0); \
            bool needmask = (kv0 + 32 * half + 31 > t0);  /* max_kv > t0 */     \
            uint32_t pw[8];                                                     \
            float l0 = 0.f, l1 = 0.f;                                           \
            _Pragma("unroll") for (int e = 0; e < 8; ++e) {                     \
                float p0 = __builtin_amdgcn_exp2f(Sv[2 * e]);                   \
                float p1 = __builtin_amdgcn_exp2f(Sv[2 * e + 1]);               \
                if (needmask) {                                                 \
                    int kv = kv0 + 32 * half + 4 * h + 2 * (e & 1) + 8 * (e >> 1); \
                    p0 = (kv     <= q) ? p0 : 0.f;                              \
                    p1 = (kv + 1 <= q) ? p1 : 0.f;                              \
                }                                                               \
                l0 += p0; l1 += p1;                                             \
                pw[e] = cvtpk(p0, p1);                                          \
            }                                                                   \
            l += l0 + l1;                                                       \
            {                                                                   \
                uint32_t a0 = pw[0], b0 = pw[2], a1 = pw[1], b1 = pw[3];        \
                asm("v_permlane32_swap_b32 %0, %1" : "+v"(a0), "+v"(b0));       \
                asm("v_permlane32_swap_b32 %0, %1" : "+v"(a1), "+v"(b1));       \
                u32x4 fr = {a0, a1, b0, b1};                                    \
                pf0 = __builtin_bit_cast(bf16x8, fr);                           \
                uint32_t c0 = pw[4], d0 = pw[6], c1 = pw[5], d1 = pw[7];        \
                asm("v_permlane32_swap_b32 %0, %1" : "+v"(c0), "+v"(d0));       \
                asm("v_permlane32_swap_b32 %0, %1" : "+v"(c1), "+v"(d1));       \
                u32x4 fr1 = {c0, c1, d0, d1};                                   \
                pf1 = __builtin_bit_cast(bf16x8, fr1);                          \
            }                                                                   \
        }

#define BODY(jj)                                                                \
    {                                                                           \
        const int kv0 = 64 * (p + 2 * (jj));                                    \
        if ((jj) + 1 < nb) STAGE(((jj) + 1) & 1, kv0 + 128);                    \
        const char* kb = smem + ((jj) & 1) * 16384;                             \
        const char* vb = kb + 8192;                                             \
        const char* krw = kb + (32 * half + ql) * 128;                          \
        bf16x8 kf0 = *(const bf16x8*)(krw + ((0 * 32 + h * 16) ^ swz));         \
        bf16x8 kf1 = *(const bf16x8*)(krw + ((1 * 32 + h * 16) ^ swz));         \
        bf16x8 kf2 = *(const bf16x8*)(krw + ((2 * 32 + h * 16) ^ swz));         \
        bf16x8 kf3 = *(const bf16x8*)(krw + ((3 * 32 + h * 16) ^ swz));         \
        bool act = (kv0 + 32 * half <= t0 + 31);                                \
        bf16x8 pf0, pf1;                                                        \
        __builtin_amdgcn_s_setprio(1);                                          \
        if (act) QK_SM(pf0, pf1)                                                \
        const char* vr0 = vb + ql * 128;                                        \
        const char* vr1 = vb + (32 + ql) * 128;                                 \
        int vc0 = (64 * half + 16 * h) ^ swz;                                   \
        int vc1 = (64 * half + 32 + 16 * h) ^ swz;                              \
        bf16x8 vf00 = *(const bf16x8*)(vr0 + vc0);                              \
        bf16x8 vf01 = *(const bf16x8*)(vr0 + vc1);                              \
        bf16x8 vf10 = *(const bf16x8*)(vr1 + vc0);                              \
        bf16x8 vf11 = *(const bf16x8*)(vr1 + vc1);                              \
        if (act) {                                                              \
            acc0 = __builtin_amdgcn_mfma_f32_32x32x16_bf16(vf00, pf0, acc0, 0, 0, 0); \
            acc0 = __builtin_amdgcn_mfma_f32_32x32x16_bf16(vf01, pf1, acc0, 0, 0, 0); \
            acc1 = __builtin_amdgcn_mfma_f32_32x32x16_bf16(vf10, pf0, acc1, 0, 0, 0); \
            acc1 = __builtin_amdgcn_mfma_f32_32x32x16_bf16(vf11, pf1, acc1, 0, 0, 0); \
        }                                                                       \
        __builtin_amdgcn_s_setprio(0);                                          \
        __syncthreads();                                                        \
    }

    if (nb > 0) STAGE(0, 64 * p);        // prologue: first chunk -> buf 0
    __syncthreads();

    for (int j = 0; j < nb; ++j) BODY(j);
#undef BODY
#undef QK_SM
#undef STAGE

    // ---- combine: 2 partials/tile. half1 publishes, half0 absorbs+writes
    //      UNNORMALIZED partial (acc, l) to this parity's buffers.
    l += __shfl_xor(l, 32);
    float* sg = (float*)smem + tile * 2112 + lane * 33;  // 2 x [64][33] f32
    if (half == 1) {
        #pragma unroll
        for (int g = 0; g < 4; ++g) {
            *(f32x4*)(sg + 4 * g)      = f32x4{acc0[4*g+0], acc0[4*g+1], acc0[4*g+2], acc0[4*g+3]};
            *(f32x4*)(sg + 16 + 4 * g) = f32x4{acc1[4*g+0], acc1[4*g+1], acc1[4*g+2], acc1[4*g+3]};
        }
        sg[32] = l;
    }
    __syncthreads();
    if (half == 0) {
        #pragma unroll
        for (int g = 0; g < 4; ++g) {
            f32x4 u0 = *(f32x4*)(sg + 4 * g);
            f32x4 u1 = *(f32x4*)(sg + 16 + 4 * g);
            acc0[4*g+0] += u0[0]; acc0[4*g+1] += u0[1]; acc0[4*g+2] += u0[2]; acc0[4*g+3] += u0[3];
            acc1[4*g+0] += u1[0]; acc1[4*g+1] += u1[1]; acc1[4*g+2] += u1[2]; acc1[4*g+3] += u1[3];
        }
        l += sg[32];
        int head = bh & 1, bb = bh >> 1;
        float* Pdst = p ? P1 : Hf;
        float* Ldst = p ? L1 : L0;
        float* hp = Pdst + ((size_t)(bb * T_SEQ) + t0 + ql) * 128 + head * 64 + 4 * h;
        #pragma unroll
        for (int g2 = 0; g2 < 4; ++g2) {
            f32x4 s0 = { acc0[g2*4+0], acc0[g2*4+1], acc0[g2*4+2], acc0[g2*4+3] };
            *(f32x4*)(hp + 8 * g2) = s0;               // d = 8*g2+4h+0..3
            f32x4 s1 = { acc1[g2*4+0], acc1[g2*4+1], acc1[g2*4+2], acc1[g2*4+3] };
            *(f32x4*)(hp + 32 + 8 * g2) = s1;          // d = 32+8*g2+4h+0..3
        }
        if (h == 0)                       // one lane per q-row
            Ldst[(size_t)bh * T_SEQ + t0 + ql] = l;
    }
}

// ---------------------------------------------------------------------------
// Kernel 3: out = ((P0+P1) * 1/(L0+L1)) @ Wout -> f32 (in place over P0).
// Row-block-diagonal: each wave reads only its own 16 rows before writing.
// Normalization folded into the bf16 fragment build (per-head rl).
// ---------------------------------------------------------------------------
__global__ __launch_bounds__(256) void out_proj(
    const float* P0, const float* __restrict__ P1,
    const float* __restrict__ L0, const float* __restrict__ L1,
    const short* __restrict__ Wt, float* out)
{
    __shared__ __align__(16) char lws[32768];
    int tid = threadIdx.x;
    int w = tid >> 6, lane = tid & 63, c = lane & 15, g = lane >> 4;
    int cs = c & 7;
    #pragma unroll
    for (int z = 0; z < 8; ++z)
        __builtin_amdgcn_global_load_lds((gptr_t)(Wt + z * 2048 + w * 512 + lane * 8),
                                         (lptr_t)(lws + z * 4096 + w * 1024), 16, 0, 0);
    __syncthreads();

    int row0 = blockIdx.x * 64 + w * 16;
    int r = row0 + c;
    int b = r >> 12, t = r & (T_SEQ - 1);
    float rl0 = 1.0f / (L0[(size_t)(b * 2 + 0) * T_SEQ + t] + L1[(size_t)(b * 2 + 0) * T_SEQ + t]);
    float rl1 = 1.0f / (L0[(size_t)(b * 2 + 1) * T_SEQ + t] + L1[(size_t)(b * 2 + 1) * T_SEQ + t]);

    bf16x8 af[4];
    const float* hp0 = P0 + (size_t)r * 128 + g * 8;
    const float* hp1 = P1 + (size_t)r * 128 + g * 8;
    #pragma unroll
    for (int kc = 0; kc < 4; ++kc) {
        float rl = (kc < 2) ? rl0 : rl1;          // d = kc*32+g*8+.. ; head = d>>6
        f32x4 x0 = *(const f32x4*)(hp0 + kc * 32);
        f32x4 x1 = *(const f32x4*)(hp0 + kc * 32 + 4);
        f32x4 y0 = *(const f32x4*)(hp1 + kc * 32);
        f32x4 y1 = *(const f32x4*)(hp1 + kc * 32 + 4);
        u32x4 wv = { cvtpk((x0[0]+y0[0])*rl, (x0[1]+y0[1])*rl),
                     cvtpk((x0[2]+y0[2])*rl, (x0[3]+y0[3])*rl),
                     cvtpk((x1[0]+y1[0])*rl, (x1[1]+y1[1])*rl),
                     cvtpk((x1[2]+y1[2])*rl, (x1[3]+y1[3])*rl) };
        af[kc] = __builtin_bit_cast(bf16x8, wv);
    }
    #pragma unroll
    for (int jt = 0; jt < 8; ++jt) {
        f32x4 accum = {0.f, 0.f, 0.f, 0.f};
        #pragma unroll
        for (int kc = 0; kc < 4; ++kc) {
            int row = jt * 16 + c;
            bf16x8 bfr = *(const bf16x8*)(lws + row * 256 + (((kc * 4 + g) ^ cs) << 4));
            accum = __builtin_amdgcn_mfma_f32_16x16x32_bf16(af[kc], bfr, accum, 0, 0, 0);
        }
        #pragma unroll
        for (int rr = 0; rr < 4; ++rr)
            out[(size_t)(row0 + g * 4 + rr) * 128 + jt * 16 + c] = accum[rr];
    }
}

// ---------------------------------------------------------------------------
extern "C" void kernel_launch(void* const* d_in, const int* in_sizes, int n_in,
                              void* d_out, int out_size, void* d_ws, size_t ws_size,
                              hipStream_t stream)
{
    (void)in_sizes; (void)n_in; (void)out_size; (void)ws_size;
    const float* x    = (const float*)d_in[0];
    const float* Wq1  = (const float*)d_in[1];
    const float* Wk1  = (const float*)d_in[2];
    const float* Wv1  = (const float*)d_in[3];
    const float* Wq2  = (const float*)d_in[4];
    const float* Wk2  = (const float*)d_in[5];
    const float* Wv2  = (const float*)d_in[6];
    const float* Wout = (const float*)d_in[7];
    float* out = (float*)d_out;

    char* ws = (char*)d_ws;
    short* Q  = (short*)(ws);                               // 8 MiB
    short* K  = (short*)(ws + (size_t)8  * 1024 * 1024);    // 8 MiB
    short* Vt = (short*)(ws + (size_t)16 * 1024 * 1024);    // 8 MiB
    float* P1 = (float*)(ws + (size_t)24 * 1024 * 1024);    // 16 MiB partial
    float* L0 = (float*)(ws + (size_t)40 * 1024 * 1024);    // 256 KiB
    float* L1 = (float*)(ws + (size_t)40 * 1024 * 1024 + 262144);
    short* Wt = (short*)(ws + (size_t)40 * 1024 * 1024 + 524288);  // 32 KiB (own slot)
    float* Hf = out;                                        // P0 lives in d_out

    proj_all<<<2624, 256, 0, stream>>>(x, Wq1, Wk1, Wq2, Wk2, Wv1, Wv2, Wout,
                                       Q, K, Vt, Wt);
    attn    <<<2048, 256, 0, stream>>>(Q, K, Vt, Hf, P1, L0, L1);
    out_proj<<< 512, 256, 0, stream>>>(Hf, P1, L0, L1, Wt, out);
}